// Round 6
// baseline (580.872 us; speedup 1.0000x reference)
//
#include <hip/hip_runtime.h>
#include <math.h>
#include <stdint.h>

constexpr int S  = 2048;
constexpr int H  = 4096;
constexpr int NH = 32;
constexpr int HD = 128;
constexpr int H3 = 3 * H;   // 12288

typedef unsigned short u16;
typedef __bf16 bf16x8 __attribute__((ext_vector_type(8)));
typedef float  f32x4  __attribute__((ext_vector_type(4)));

// f32 -> bf16 (RNE) as raw u16
__device__ __forceinline__ u16 f2bf(float f) {
  uint32_t u = __float_as_uint(f);
  uint32_t r = (u + 0x7fff + ((u >> 16) & 1)) >> 16;
  return (u16)r;
}
__device__ __forceinline__ float bf2f(u16 u) {
  return __uint_as_float((uint32_t)u << 16);
}

// async global->LDS, 16B per lane. LDS dest = wave-uniform base + lane*16.
__device__ __forceinline__ void load_lds16(const void* g, void* l) {
  __builtin_amdgcn_global_load_lds(
      (__attribute__((address_space(1))) void*)(uintptr_t)g,
      (__attribute__((address_space(3))) void*)l,
      16, 0, 0);
}

// ---------------------------------------------------------------------------
// cast f32 -> bf16, vectorized (n % 4 == 0)
// ---------------------------------------------------------------------------
__global__ __launch_bounds__(256)
void castk(const float* __restrict__ in, u16* __restrict__ out, int n4) {
  for (int i = blockIdx.x * 256 + threadIdx.x; i < n4; i += gridDim.x * 256) {
    float4 v = ((const float4*)in)[i];
    ushort4 o;
    o.x = f2bf(v.x); o.y = f2bf(v.y); o.z = f2bf(v.z); o.w = f2bf(v.w);
    ((ushort4*)out)[i] = o;
  }
}

// ---------------------------------------------------------------------------
// Deep-pipelined MFMA GEMM: C[M][NCOLS] = A[M][4096] @ W[NCOLS][4096]^T + bias.
// 256 threads = 4 waves (2Mx2N), per-wave tile (TM*16)x(TN*16).
// QKV: BM=256,BN=128,TM=8,TN=4 -> 12 ds_read/32 MFMA per K-step (384 B/MFMA,
//   LDS-BW ceiling ~89%); 72 KiB LDS -> 2 blocks/CU (2 waves/SIMD).
// Dense: BM=BN=128,TM=TN=4; 48 KiB -> 3 blocks/CU.
// 3 LDS buffers, prefetch 2 K-tiles ahead, one s_barrier + counted
// vmcnt(L) per K-tile (L = loads/thread/tile; drains current tile only).
// T2 swizzle (verified 0-conflict in r5): phys_chunk = logical ^ ((row>>1)&3),
// rule #21 (linear gload_lds dest + inverse-swizzled source + swizzled read).
// T1 bijective XCD swizzle (grid % 8 == 0). T5 setprio around MFMA cluster.
// ---------------------------------------------------------------------------
template<int BM, int BN, int TM, int TN, int NCOLS, int OUT_BF16>
__global__ __launch_bounds__(256, 2)
void gemmP(const u16* __restrict__ A, const u16* __restrict__ W,
           const float* __restrict__ bias, void* __restrict__ Cout) {
  constexpr int K = 4096;
  constexpr int NT = K / 32;            // 128 K-tiles
  constexpr int NTN = NCOLS / BN;       // N-tiles in grid
  constexpr int LA = BM / 64;           // A loads per thread per tile
  constexpr int LB = BN / 64;
  constexpr int L = LA + LB;
  __shared__ __attribute__((aligned(16))) unsigned char sA[3][BM * 64];
  __shared__ __attribute__((aligned(16))) unsigned char sB[3][BN * 64];
  const int tid = threadIdx.x, wave = tid >> 6, lane = tid & 63;
  const int l15 = lane & 15, l4 = lane >> 4;
  const int wr = wave >> 1, wc = wave & 1;

  const int nwg = gridDim.x, bid = blockIdx.x;
  const int cpx = nwg >> 3;                       // nwg % 8 == 0
  const int swz = (bid & 7) * cpx + (bid >> 3);
  const int by = swz / NTN, bx = swz - by * NTN;
  const int bm = by * BM, bn = bx * BN;

  // staging: lane covers row (lane>>2) of a 16-row group, phys chunk (lane&3);
  // global source supplies logical chunk (lane&3) ^ ((row>>1)&3)
  const int srow = lane >> 2;
  const int sck  = ((lane & 3) ^ ((lane >> 3) & 3)) * 8;  // element offset

  auto stage = [&](int u, int b) {
    const int k0 = u * 32;
#pragma unroll
    for (int s2 = 0; s2 < LA; ++s2) {
      const int rl = s2 * 64 + wave * 16;
      load_lds16(A + (size_t)(bm + rl + srow) * K + k0 + sck, &sA[b][rl * 64]);
    }
#pragma unroll
    for (int s2 = 0; s2 < LB; ++s2) {
      const int rl = s2 * 64 + wave * 16;
      load_lds16(W + (size_t)(bn + rl + srow) * K + k0 + sck, &sB[b][rl * 64]);
    }
  };

  f32x4 acc[TM][TN];
#pragma unroll
  for (int i = 0; i < TM; ++i)
#pragma unroll
    for (int j = 0; j < TN; ++j) acc[i][j] = (f32x4)0.f;

  stage(0, 0); stage(1, 1);                        // 2L loads in flight

  const int cksw = (l4 ^ ((l15 >> 1) & 3)) * 16;   // swizzled 16B chunk offset

  int bR = 0, bW = 2;
  for (int t = 0; t < NT; ++t) {
    if (t < NT - 1) {
      if constexpr (L == 6) asm volatile("s_waitcnt vmcnt(6)" ::: "memory");
      else                  asm volatile("s_waitcnt vmcnt(4)" ::: "memory");
    } else {
      asm volatile("s_waitcnt vmcnt(0)" ::: "memory");
    }
    __builtin_amdgcn_sched_barrier(0);
    __builtin_amdgcn_s_barrier();
    __builtin_amdgcn_sched_barrier(0);

    bf16x8 af[TM], bf[TN];
#pragma unroll
    for (int mi = 0; mi < TM; ++mi)
      af[mi] = *(const bf16x8*)&sA[bR][(wr * (TM * 16) + mi * 16 + l15) * 64 + cksw];
#pragma unroll
    for (int ni = 0; ni < TN; ++ni)
      bf[ni] = *(const bf16x8*)&sB[bR][(wc * (TN * 16) + ni * 16 + l15) * 64 + cksw];

    if (t <= NT - 3) stage(t + 2, bW);             // prefetch 2 tiles ahead

    __builtin_amdgcn_s_setprio(1);
#pragma unroll
    for (int mi = 0; mi < TM; ++mi)
#pragma unroll
      for (int ni = 0; ni < TN; ++ni)
        acc[mi][ni] = __builtin_amdgcn_mfma_f32_16x16x32_bf16(af[mi], bf[ni], acc[mi][ni], 0, 0, 0);
    __builtin_amdgcn_s_setprio(0);

    bR = (bR == 2) ? 0 : bR + 1;
    bW = (bW == 2) ? 0 : bW + 1;
  }

  // epilogue: bias + store
#pragma unroll
  for (int ni = 0; ni < TN; ++ni) {
    const int col = bn + wc * (TN * 16) + ni * 16 + l15;
    const float bv = bias[col];
#pragma unroll
    for (int mi = 0; mi < TM; ++mi) {
#pragma unroll
      for (int r = 0; r < 4; ++r) {
        const int row = bm + wr * (TM * 16) + mi * 16 + l4 * 4 + r;
        const float v = acc[mi][ni][r] + bv;
        if (OUT_BF16) ((u16*)Cout)[(size_t)row * NCOLS + col] = f2bf(v);
        else          ((float*)Cout)[(size_t)row * NCOLS + col] = v;
      }
    }
  }
}

// ---------------------------------------------------------------------------
// Rotary from bf16 qkv [S][H3] (per-head q|k|v of 128) -> Qb,Kb [NH][S][HD] bf16.
// Q additionally scaled by log2(e)/sqrt(HD) (layer coeff cancels in softmax).
// ---------------------------------------------------------------------------
__global__ __launch_bounds__(128)
void rotary(const u16* __restrict__ qkv, u16* __restrict__ Qb, u16* __restrict__ Kb) {
  const int s = blockIdx.x, h = blockIdx.y, d = threadIdx.x;
  const u16* base = qkv + (size_t)s * H3 + h * 384;
  const float qv = bf2f(base[d]);
  const float kv = bf2f(base[128 + d]);
  const float qp = bf2f(base[d ^ 32]);
  const float kp = bf2f(base[128 + (d ^ 32)]);
  const int dd = d & 63, j = dd & 31;
  const float invf = exp2f(-(float)j * (13.287712379549449f / 32.f));
  float sn, c;
  sincosf((float)s * invf, &sn, &c);
  const float sign = (dd < 32) ? -1.f : 1.f;
  const float qo = qv * c + sign * qp * sn;
  const float ko = kv * c + sign * kp * sn;
  const size_t o = ((size_t)h * S + s) * HD + d;
  Qb[o] = f2bf(qo * 0.12751721769218683f);  // log2(e)/sqrt(128)
  Kb[o] = f2bf(ko);
}

// ---------------------------------------------------------------------------
// V transpose: Vt[NH][HD][S] <- qkv[s][h*384+256+d], 64-row tiles via LDS.
// ---------------------------------------------------------------------------
__global__ __launch_bounds__(256)
void transpose_v(const u16* __restrict__ qkv, u16* __restrict__ Vt) {
  __shared__ u16 tile[64][130];
  const int s0 = blockIdx.x * 64, h = blockIdx.y;
  for (int idx = threadIdx.x; idx < 64 * 128; idx += 256) {
    const int r = idx >> 7, c = idx & 127;
    tile[r][c] = qkv[(size_t)(s0 + r) * H3 + h * 384 + 256 + c];
  }
  __syncthreads();
  for (int idx = threadIdx.x; idx < 128 * 64; idx += 256) {
    const int d = idx >> 6, c = idx & 63;
    Vt[((size_t)h * HD + d) * S + s0 + c] = tile[c][d];
  }
}

// ---------------------------------------------------------------------------
// Flash attention, causal. Block = (qb: 64 q-rows, head h), 4 waves x 16 rows.
// ---------------------------------------------------------------------------
__global__ __launch_bounds__(256)
void attn(const u16* __restrict__ Qb, const u16* __restrict__ Kb,
          const u16* __restrict__ Vt, u16* __restrict__ ctx) {
  __shared__ __attribute__((aligned(16))) unsigned char sK[64 * 256];
  __shared__ __attribute__((aligned(16))) unsigned char sV[128 * 128];
  __shared__ __attribute__((aligned(16))) unsigned char sP[4][16 * 128];
  const int qb = blockIdx.x, h = blockIdx.y;
  const int tid = threadIdx.x, wave = tid >> 6, lane = tid & 63;
  const int l15 = lane & 15, l4 = lane >> 4;
  const int qw0 = qb * 64 + wave * 16;

  bf16x8 qf[4];
  {
    const u16* qrow = Qb + ((size_t)h * S + qw0 + l15) * HD;
#pragma unroll
    for (int ks = 0; ks < 4; ++ks)
      qf[ks] = *(const bf16x8*)(qrow + ks * 32 + l4 * 8);
  }

  f32x4 of[8];
#pragma unroll
  for (int i = 0; i < 8; ++i) of[i] = (f32x4)0.f;
  float mrun[4] = {-1e30f, -1e30f, -1e30f, -1e30f};
  float lrun[4] = {0.f, 0.f, 0.f, 0.f};

  const int nt = qb + 1;
  for (int it = 0; it < nt; ++it) {
    const int t0 = it * 64;
#pragma unroll
    for (int c = 0; c < 4; ++c) {
      const int rbase = c * 16 + wave * 4;
      const int rr = rbase + (lane >> 4);
      const int p = lane & 15;
      load_lds16(Kb + ((size_t)h * S + t0 + rr) * HD + ((p ^ (rr & 15)) * 8),
                 &sK[rbase * 256]);
    }
#pragma unroll
    for (int c = 0; c < 4; ++c) {
      const int rbase = c * 32 + wave * 8;
      const int rr = rbase + (lane >> 3);
      const int p = lane & 7;
      load_lds16(Vt + ((size_t)h * HD + rr) * S + t0 + ((p ^ (rr & 7)) * 8),
                 &sV[rbase * 128]);
    }
    __syncthreads();

    f32x4 sc[4];
#pragma unroll
    for (int nf = 0; nf < 4; ++nf) sc[nf] = (f32x4)0.f;
#pragma unroll
    for (int nf = 0; nf < 4; ++nf) {
      const int trow = nf * 16 + l15;
#pragma unroll
      for (int ks = 0; ks < 4; ++ks) {
        const int chunk = ks * 4 + l4;
        bf16x8 kf = *(const bf16x8*)&sK[trow * 256 + ((chunk ^ (trow & 15)) * 16)];
        sc[nf] = __builtin_amdgcn_mfma_f32_16x16x32_bf16(qf[ks], kf, sc[nf], 0, 0, 0);
      }
    }

    if (t0 == qb * 64) {
#pragma unroll
      for (int nf = 0; nf < 4; ++nf) {
        const int tg = t0 + nf * 16 + l15;
#pragma unroll
        for (int r = 0; r < 4; ++r) {
          const int sg = qw0 + l4 * 4 + r;
          if (tg > sg) sc[nf][r] = -1e30f;
        }
      }
    }

    f32x4 vm = sc[0];
#pragma unroll
    for (int nf = 1; nf < 4; ++nf)
#pragma unroll
      for (int r = 0; r < 4; ++r) vm[r] = fmaxf(vm[r], sc[nf][r]);
#pragma unroll
    for (int m = 1; m <= 8; m <<= 1)
#pragma unroll
      for (int r = 0; r < 4; ++r) vm[r] = fmaxf(vm[r], __shfl_xor(vm[r], m, 64));

    float scale[4];
#pragma unroll
    for (int r = 0; r < 4; ++r) {
      const float nm = fmaxf(mrun[r], vm[r]);
      scale[r] = exp2f(mrun[r] - nm);
      mrun[r] = nm;
    }

    f32x4 rs = (f32x4)0.f;
#pragma unroll
    for (int nf = 0; nf < 4; ++nf) {
#pragma unroll
      for (int r = 0; r < 4; ++r) {
        const float p = exp2f(sc[nf][r] - mrun[r]);
        rs[r] += p;
        const int row = l4 * 4 + r;
        const int t = nf * 16 + l15;
        const int chunk = t >> 3;
        *(u16*)&sP[wave][row * 128 + ((chunk ^ (row & 7)) * 16) + (t & 7) * 2] = f2bf(p);
      }
    }
#pragma unroll
    for (int m = 1; m <= 8; m <<= 1)
#pragma unroll
      for (int r = 0; r < 4; ++r) rs[r] += __shfl_xor(rs[r], m, 64);
#pragma unroll
    for (int r = 0; r < 4; ++r) lrun[r] = lrun[r] * scale[r] + rs[r];
#pragma unroll
    for (int i = 0; i < 8; ++i)
#pragma unroll
      for (int r = 0; r < 4; ++r) of[i][r] *= scale[r];

    asm volatile("s_waitcnt lgkmcnt(0)" ::: "memory");
    __builtin_amdgcn_sched_barrier(0);

    bf16x8 pa[2];
#pragma unroll
    for (int ksP = 0; ksP < 2; ++ksP) {
      const int chunk = ksP * 4 + l4;
      pa[ksP] = *(const bf16x8*)&sP[wave][l15 * 128 + ((chunk ^ (l15 & 7)) * 16)];
    }
#pragma unroll
    for (int nf2 = 0; nf2 < 8; ++nf2) {
      const int d = nf2 * 16 + l15;
#pragma unroll
      for (int ksP = 0; ksP < 2; ++ksP) {
        const int chunk = ksP * 4 + l4;
        bf16x8 vf = *(const bf16x8*)&sV[d * 128 + ((chunk ^ (d & 7)) * 16)];
        of[nf2] = __builtin_amdgcn_mfma_f32_16x16x32_bf16(pa[ksP], vf, of[nf2], 0, 0, 0);
      }
    }
    __syncthreads();
  }

  float invr[4];
#pragma unroll
  for (int r = 0; r < 4; ++r) invr[r] = 1.f / lrun[r];
#pragma unroll
  for (int nf2 = 0; nf2 < 8; ++nf2) {
    const int d = nf2 * 16 + l15;
#pragma unroll
    for (int r = 0; r < 4; ++r) {
      const int srow = qw0 + l4 * 4 + r;
      ctx[(size_t)srow * H + h * HD + d] = f2bf(of[nf2][r] * invr[r]);
    }
  }
}

// ---------------------------------------------------------------------------
extern "C" void kernel_launch(void* const* d_in, const int* in_sizes, int n_in,
                              void* d_out, int out_size, void* d_ws, size_t ws_size,
                              hipStream_t stream) {
  (void)in_sizes; (void)n_in; (void)out_size; (void)ws_size;
  const float* hidden  = (const float*)d_in[0];
  const float* w_qkv   = (const float*)d_in[4];
  const float* b_qkv   = (const float*)d_in[5];
  const float* w_dense = (const float*)d_in[6];
  const float* b_dense = (const float*)d_in[7];
  float* out = (float*)d_out;

  char* ws = (char*)d_ws;
  u16* wqkvb   = (u16*)(ws + 0);                       // 100.66 MB
  u16* wdenseb = (u16*)(ws + 0);                       // after gemm1 (33.55 MB)
  u16* ctxb    = (u16*)(ws + 41943040);                // 16.78 MB
  u16* hb      = (u16*)(ws + 100663296);               // 16.78 MB
  u16* qkvb    = (u16*)(ws + 117440512);               // 50.33 MB
  u16* Qbp     = (u16*)(ws + 167772160);               // 16.78 MB
  u16* Kbp     = (u16*)(ws + 184549376);               // 16.78 MB
  u16* Vtp     = (u16*)(ws + 201326592);               // 16.78 MB

  castk<<<2048, 256, 0, stream>>>(w_qkv, wqkvb, (H3 * H) / 4);
  castk<<<2048, 256, 0, stream>>>(hidden, hb, (S * H) / 4);
  // QKV: 256x128 tiles -> 8 x 96 = 768 blocks = 3/CU, 2 blocks/CU resident
  gemmP<256, 128, 8, 4, H3, 1><<<dim3(768), 256, 0, stream>>>(hb, wqkvb, b_qkv, qkvb);
  rotary<<<dim3(S, NH), 128, 0, stream>>>(qkvb, Qbp, Kbp);
  transpose_v<<<dim3(S / 64, NH), 256, 0, stream>>>(qkvb, Vtp);
  castk<<<2048, 256, 0, stream>>>(w_dense, wdenseb, (H * H) / 4);
  attn<<<dim3(S / 64, NH), 256, 0, stream>>>(Qbp, Kbp, Vtp, ctxb);
  // dense: 128x128 tiles -> 16 x 32 = 512 blocks = 2/CU, 3 blocks/CU capacity
  gemmP<128, 128, 4, 4, H, 0><<<dim3(512), 256, 0, stream>>>(ctxb, wdenseb, b_dense, out);
}